// Round 12
// baseline (981.794 us; speedup 1.0000x reference)
//
#include <hip/hip_runtime.h>
#include <hip/hip_cooperative_groups.h>

namespace cg = cooperative_groups;

// GCN 2-layer forward in ONE cooperative dispatch (kills ~10us/dispatch gaps).
// Phases (grid.sync between): 0 zero cursors -> A part||mm1 -> B build ->
// B' scale hs1 by dinv -> C agg1 -> D mm2 -> E agg2.
// CSR via 2-level bucket sort; payloads bf16 stride-64 (128B rows);
// aggregation = 4-edges-per-gather (ushort4 lanes, shfl offsets).

#define FIN 128
#define F1  64
#define F2  41
#define FP  64

#define BSH    8                 // bucket = dst >> 8
#define BCAP   6144              // per-bucket window (mean 4096, >30 sigma)
#define NBMAX  512
#define CHUNK_P 4096             // edges per part unit (16/thread)

#define MT 128                   // GEMM M-tile
#define KC 16                    // GEMM K-chunk

#define SMEM_BYTES 29952         // union: part 29.7K / mm1 24.6K / build 27.1K

__device__ __forceinline__ unsigned short f2bf(float f) {
    unsigned u = __builtin_bit_cast(unsigned, f);
    u += 0x7FFFu + ((u >> 16) & 1u);           // RNE
    return (unsigned short)(u >> 16);
}
__device__ __forceinline__ float bf2f(unsigned short h) {
    unsigned u = ((unsigned)h) << 16;
    return __builtin_bit_cast(float, u);
}

__global__ __launch_bounds__(256) void k_all(
    const int* __restrict__ src, const int* __restrict__ dst,
    const float* __restrict__ x, const float* __restrict__ W1,
    const float* __restrict__ b1, const float* __restrict__ W2,
    const float* __restrict__ b2, float* __restrict__ out,
    int* __restrict__ gcur, int* __restrict__ pairs, int* __restrict__ adj,
    int2* __restrict__ rowinfo, float* __restrict__ dinv,
    unsigned short* __restrict__ hs1, unsigned short* __restrict__ hs2,
    unsigned short* __restrict__ h1b,
    int n, int E, int nchunks, int nmm, int nbuck, int nagg) {
    cg::grid_group gg = cg::this_grid();
    __shared__ alignas(16) char smem[SMEM_BYTES];
    const int tid = threadIdx.x;
    const int NB  = gridDim.x;

    // ---- phase 0: zero bucket cursors + adj cursor -------------------------
    {
        int i = blockIdx.x * 256 + tid;
        if (i <= NBMAX) gcur[i] = 0;
    }
    gg.sync();

    // ---- phase A: units [0,nchunks) = part, [nchunks,nchunks+nmm) = mm1 ----
    for (int unit = blockIdx.x; unit < nchunks + nmm; unit += NB) {
        __syncthreads();
        if (unit < nchunks) {
            // ---------------- PART ----------------
            int* hist = (int*)smem;                 // NBMAX
            int* gsh  = hist + NBMAX;               // NBMAX
            int* lex  = gsh + NBMAX;                // 256
            int* stot = lex + 256;                  // 4
            int* limg = stot + 4;                   // CHUNK_P (16 KB)
            unsigned short* bid = (unsigned short*)(limg + CHUNK_P);  // 8 KB
            int e0 = unit * CHUNK_P;
            int ds[CHUNK_P / 256], ss[CHUNK_P / 256];
#pragma unroll
            for (int j = 0; j < CHUNK_P / 256; j++) {
                int e = e0 + j * 256 + tid;
                if (e < E) { ds[j] = dst[e]; ss[j] = src[e]; } else ds[j] = -1;
            }
            hist[tid] = 0; hist[tid + 256] = 0;
            __syncthreads();
#pragma unroll
            for (int j = 0; j < CHUNK_P / 256; j++)
                if (ds[j] >= 0) atomicAdd(&hist[ds[j] >> BSH], 1);
            __syncthreads();
            int b0 = 2 * tid, b1i = 2 * tid + 1;
            int c0 = hist[b0], c1 = hist[b1i];
            int s  = c0 + c1;
            lex[tid] = s;
            __syncthreads();
            for (int off = 1; off < 256; off <<= 1) {
                int v = lex[tid];
                int a = (tid >= off) ? lex[tid - off] : 0;
                __syncthreads();
                lex[tid] = v + a;
                __syncthreads();
            }
            int incl = lex[tid];
            if (tid == 255) stot[0] = incl;
            int ex = incl - s;
            int g0 = c0 ? atomicAdd(&gcur[b0], c0) : 0;
            int g1 = c1 ? atomicAdd(&gcur[b1i], c1) : 0;
            hist[b0]  = ex; hist[b1i] = ex + c0;
            gsh[b0]   = b0 * BCAP + g0 - ex;
            gsh[b1i]  = b1i * BCAP + g1 - (ex + c0);
            __syncthreads();
#pragma unroll
            for (int j = 0; j < CHUNK_P / 256; j++) {
                if (ds[j] >= 0) {
                    int b = ds[j] >> BSH;
                    int p = atomicAdd(&hist[b], 1);
                    limg[p] = (ss[j] << BSH) | (ds[j] & 255);
                    bid[p]  = (unsigned short)b;
                }
            }
            __syncthreads();
            int tot = stot[0];
            for (int k = tid; k < tot; k += 256)
                pairs[k + gsh[bid[k]]] = limg[k];
        } else {
            // ---------------- MM1: hs1 = bf16(x @ W1), UNSCALED ----------------
            float* Ws = (float*)smem;                           // 16 KB (half W1)
            float (*As)[MT] = (float(*)[MT])(smem + 64 * F1 * 4);  // 8 KB
            int n0 = (unit - nchunks) * MT;
            int m0 = (tid & 15) * 8;
            int c0 = (tid >> 4) * 4;
            int m_l = tid & 127;
            int kh  = (tid >> 7) * 8;
            bool mvalid = (n0 + m_l) < n;
            float acc[8][4] = {};
            for (int half = 0; half < 2; half++) {
                __syncthreads();
#pragma unroll
                for (int j = 0; j < 4; j++) {
                    int f = j * 256 + tid;
                    ((float4*)Ws)[f] = ((const float4*)W1)[half * 1024 + f];
                }
                const float* xrow = x + (size_t)(n0 + m_l) * FIN + half * 64 + kh;
                for (int kc = 0; kc < 64; kc += KC) {
                    __syncthreads();
                    float4 v0 = mvalid ? *(const float4*)(xrow + kc)     : float4{0.f,0.f,0.f,0.f};
                    float4 v1 = mvalid ? *(const float4*)(xrow + kc + 4) : float4{0.f,0.f,0.f,0.f};
                    As[kh + 0][m_l] = v0.x; As[kh + 1][m_l] = v0.y;
                    As[kh + 2][m_l] = v0.z; As[kh + 3][m_l] = v0.w;
                    As[kh + 4][m_l] = v1.x; As[kh + 5][m_l] = v1.y;
                    As[kh + 6][m_l] = v1.z; As[kh + 7][m_l] = v1.w;
                    __syncthreads();
#pragma unroll
                    for (int k = 0; k < KC; k++) {
                        float4 a0 = *(const float4*)&As[k][m0];
                        float4 a1 = *(const float4*)&As[k][m0 + 4];
                        float4 w  = *(const float4*)&Ws[(kc + k) * F1 + c0];
                        float a[8] = {a0.x, a0.y, a0.z, a0.w, a1.x, a1.y, a1.z, a1.w};
#pragma unroll
                        for (int i = 0; i < 8; i++) {
                            acc[i][0] += a[i] * w.x;
                            acc[i][1] += a[i] * w.y;
                            acc[i][2] += a[i] * w.z;
                            acc[i][3] += a[i] * w.w;
                        }
                    }
                }
            }
#pragma unroll
            for (int i = 0; i < 8; i++) {
                int node = n0 + m0 + i;
                if (node < n) {
                    ushort4 o = { f2bf(acc[i][0]), f2bf(acc[i][1]),
                                  f2bf(acc[i][2]), f2bf(acc[i][3]) };
                    *(ushort4*)&hs1[((size_t)node << 6) + c0] = o;
                }
            }
        }
    }
    __threadfence();
    gg.sync();

    // ---- phase B: per-bucket CSR build -------------------------------------
    for (int b = blockIdx.x; b < nbuck; b += NB) {
        __syncthreads();
        int* lcnt = (int*)smem;            // 256
        int* lex  = lcnt + 256;            // 256
        int* lcur = lex + 256;             // 256
        int* ladj = lcur + 256;            // BCAP (24 KB)
        int* sbase = ladj + BCAP;          // 1
        int cntb = gcur[b]; if (cntb > BCAP) cntb = BCAP;
        int node0 = b << BSH;
        const int* pb = pairs + (size_t)b * BCAP;
        if (tid == 0) sbase[0] = atomicAdd(&gcur[NBMAX], cntb);
        lcnt[tid] = 0;
        __syncthreads();
        for (int k = tid; k < cntb; k += 256) atomicAdd(&lcnt[pb[k] & 255], 1);
        __syncthreads();
        int own = lcnt[tid];
        lex[tid] = own;
        __syncthreads();
        for (int off = 1; off < 256; off <<= 1) {
            int val = lex[tid];
            int add = (tid >= off) ? lex[tid - off] : 0;
            __syncthreads();
            lex[tid] = val + add;
            __syncthreads();
        }
        int excl = lex[tid] - own;
        __syncthreads();
        lcur[tid] = excl;
        __syncthreads();
        for (int k = tid; k < cntb; k += 256) {
            int pk  = pb[k];
            int pos = atomicAdd(&lcur[pk & 255], 1);
            ladj[pos] = pk >> BSH;
        }
        __syncthreads();
        int base = sbase[0];
        for (int k = tid; k < cntb; k += 256) adj[base + k] = ladj[k];
        int node = node0 + tid;
        if (node < n) {
            rowinfo[node] = make_int2(base + excl, own);
            dinv[node]    = rsqrtf((float)own + 1.0f);
        }
    }
    __threadfence();
    gg.sync();

    // ---- phase B': hs1 *= dinv[node] (in place, coalesced 16B/thread) ------
    {
        int total = n * 8;   // 8 bf16 per unit
        for (int u = blockIdx.x * 256 + tid; u < total; u += NB * 256) {
            int node = u >> 3;
            int q = (u & 7) * 8;
            float dv = dinv[node];
            ushort4* p0 = (ushort4*)&hs1[((size_t)node << 6) + q];
            ushort4 a = p0[0], b4 = p0[1];
            a.x = f2bf(bf2f(a.x) * dv);  a.y = f2bf(bf2f(a.y) * dv);
            a.z = f2bf(bf2f(a.z) * dv);  a.w = f2bf(bf2f(a.w) * dv);
            b4.x = f2bf(bf2f(b4.x) * dv); b4.y = f2bf(bf2f(b4.y) * dv);
            b4.z = f2bf(bf2f(b4.z) * dv); b4.w = f2bf(bf2f(b4.w) * dv);
            p0[0] = a; p0[1] = b4;
        }
    }
    __threadfence();
    gg.sync();

    // ---- phase C: agg1  h1 = bf16(relu(dinv*(gather+self) + b1)) -----------
    {
        int lane = tid & 63;
        int grp  = lane >> 4;
        int p4   = (lane & 15) * 4;
        for (int u = blockIdx.x; u < nagg; u += NB) {
            int node = u * 4 + (tid >> 6);
            if (node >= n) continue;
            int2 ri = rowinfo[node];
            int beg = ri.x, deg = ri.y;
            float4 acc = {0.f, 0.f, 0.f, 0.f};
            if (grp == 0) {
                ushort4 uu = *(const ushort4*)&hs1[((size_t)node << 6) + p4];
                acc.x = bf2f(uu.x); acc.y = bf2f(uu.y);
                acc.z = bf2f(uu.z); acc.w = bf2f(uu.w);
            }
            for (int base = 0; base < deg; base += 64) {
                int m = deg - base; if (m > 64) m = 64;
                int idx = beg + base + lane;
                int myoff = adj[idx < E ? idx : 0] << 6;
                int e = 0;
                for (; e + 16 <= m; e += 16) {
                    int o0 = __shfl(myoff, e + grp),     o1 = __shfl(myoff, e + 4 + grp);
                    int o2 = __shfl(myoff, e + 8 + grp), o3 = __shfl(myoff, e + 12 + grp);
                    ushort4 u0 = *(const ushort4*)&hs1[(size_t)o0 + p4];
                    ushort4 u1 = *(const ushort4*)&hs1[(size_t)o1 + p4];
                    ushort4 u2 = *(const ushort4*)&hs1[(size_t)o2 + p4];
                    ushort4 u3 = *(const ushort4*)&hs1[(size_t)o3 + p4];
                    acc.x += (bf2f(u0.x) + bf2f(u1.x)) + (bf2f(u2.x) + bf2f(u3.x));
                    acc.y += (bf2f(u0.y) + bf2f(u1.y)) + (bf2f(u2.y) + bf2f(u3.y));
                    acc.z += (bf2f(u0.z) + bf2f(u1.z)) + (bf2f(u2.z) + bf2f(u3.z));
                    acc.w += (bf2f(u0.w) + bf2f(u1.w)) + (bf2f(u2.w) + bf2f(u3.w));
                }
                for (; e < m; e += 4) {
                    int sl = e + grp;
                    int o = __shfl(myoff, sl);
                    if (sl < m) {
                        ushort4 uu = *(const ushort4*)&hs1[(size_t)o + p4];
                        acc.x += bf2f(uu.x); acc.y += bf2f(uu.y);
                        acc.z += bf2f(uu.z); acc.w += bf2f(uu.w);
                    }
                }
            }
            acc.x += __shfl_xor(acc.x, 16); acc.y += __shfl_xor(acc.y, 16);
            acc.z += __shfl_xor(acc.z, 16); acc.w += __shfl_xor(acc.w, 16);
            acc.x += __shfl_xor(acc.x, 32); acc.y += __shfl_xor(acc.y, 32);
            acc.z += __shfl_xor(acc.z, 32); acc.w += __shfl_xor(acc.w, 32);
            if (grp == 0) {
                float dvn = dinv[node];
                float4 bg = *(const float4*)&b1[p4];
                float vx = acc.x * dvn + bg.x; vx = vx > 0.f ? vx : 0.f;
                float vy = acc.y * dvn + bg.y; vy = vy > 0.f ? vy : 0.f;
                float vz = acc.z * dvn + bg.z; vz = vz > 0.f ? vz : 0.f;
                float vw = acc.w * dvn + bg.w; vw = vw > 0.f ? vw : 0.f;
                ushort4 o = { f2bf(vx), f2bf(vy), f2bf(vz), f2bf(vw) };
                *(ushort4*)&h1b[((size_t)node << 6) + p4] = o;
            }
        }
    }
    __threadfence();
    gg.sync();

    // ---- phase D: mm2  hs2 = bf16((h1 @ W2) * dinv), W2 zero-padded --------
    for (int u = blockIdx.x; u < nmm; u += NB) {
        __syncthreads();
        float* Ws = (float*)smem;                            // 16 KB
        float (*As)[MT] = (float(*)[MT])(smem + F1 * FP * 4); // 8 KB
        int n0 = u * MT;
        for (int idx = tid; idx < F1 * FP; idx += 256) {
            int k = idx >> 6, c = idx & 63;
            Ws[idx] = (c < F2) ? W2[k * F2 + c] : 0.f;
        }
        int m0 = (tid & 15) * 8;
        int c0 = (tid >> 4) * 4;
        int m_l = tid & 127;
        int kh  = (tid >> 7) * 8;
        bool mvalid = (n0 + m_l) < n;
        const unsigned short* hrow = h1b + ((size_t)(n0 + m_l) << 6) + kh;
        float acc[8][4] = {};
        for (int kc = 0; kc < F1; kc += KC) {
            __syncthreads();
            ushort4 u0 = mvalid ? *(const ushort4*)(hrow + kc)     : ushort4{0,0,0,0};
            ushort4 u1 = mvalid ? *(const ushort4*)(hrow + kc + 4) : ushort4{0,0,0,0};
            As[kh + 0][m_l] = bf2f(u0.x); As[kh + 1][m_l] = bf2f(u0.y);
            As[kh + 2][m_l] = bf2f(u0.z); As[kh + 3][m_l] = bf2f(u0.w);
            As[kh + 4][m_l] = bf2f(u1.x); As[kh + 5][m_l] = bf2f(u1.y);
            As[kh + 6][m_l] = bf2f(u1.z); As[kh + 7][m_l] = bf2f(u1.w);
            __syncthreads();
#pragma unroll
            for (int k = 0; k < KC; k++) {
                float4 a0 = *(const float4*)&As[k][m0];
                float4 a1 = *(const float4*)&As[k][m0 + 4];
                float4 w  = *(const float4*)&Ws[(kc + k) * FP + c0];
                float a[8] = {a0.x, a0.y, a0.z, a0.w, a1.x, a1.y, a1.z, a1.w};
#pragma unroll
                for (int i = 0; i < 8; i++) {
                    acc[i][0] += a[i] * w.x;
                    acc[i][1] += a[i] * w.y;
                    acc[i][2] += a[i] * w.z;
                    acc[i][3] += a[i] * w.w;
                }
            }
        }
#pragma unroll
        for (int i = 0; i < 8; i++) {
            int node = n0 + m0 + i;
            if (node < n) {
                float dv = dinv[node];
                ushort4 o = { f2bf(acc[i][0] * dv), f2bf(acc[i][1] * dv),
                              f2bf(acc[i][2] * dv), f2bf(acc[i][3] * dv) };
                *(ushort4*)&hs2[((size_t)node << 6) + c0] = o;
            }
        }
    }
    __threadfence();
    gg.sync();

    // ---- phase E: agg2  out = dinv*(gather+self) + b2 ----------------------
    {
        int lane = tid & 63;
        int grp  = lane >> 4;
        int p4   = (lane & 15) * 4;
        for (int u = blockIdx.x; u < nagg; u += NB) {
            int node = u * 4 + (tid >> 6);
            if (node >= n) continue;
            int2 ri = rowinfo[node];
            int beg = ri.x, deg = ri.y;
            float4 acc = {0.f, 0.f, 0.f, 0.f};
            if (grp == 0) {
                ushort4 uu = *(const ushort4*)&hs2[((size_t)node << 6) + p4];
                acc.x = bf2f(uu.x); acc.y = bf2f(uu.y);
                acc.z = bf2f(uu.z); acc.w = bf2f(uu.w);
            }
            for (int base = 0; base < deg; base += 64) {
                int m = deg - base; if (m > 64) m = 64;
                int idx = beg + base + lane;
                int myoff = adj[idx < E ? idx : 0] << 6;
                int e = 0;
                for (; e + 16 <= m; e += 16) {
                    int o0 = __shfl(myoff, e + grp),     o1 = __shfl(myoff, e + 4 + grp);
                    int o2 = __shfl(myoff, e + 8 + grp), o3 = __shfl(myoff, e + 12 + grp);
                    ushort4 u0 = *(const ushort4*)&hs2[(size_t)o0 + p4];
                    ushort4 u1 = *(const ushort4*)&hs2[(size_t)o1 + p4];
                    ushort4 u2 = *(const ushort4*)&hs2[(size_t)o2 + p4];
                    ushort4 u3 = *(const ushort4*)&hs2[(size_t)o3 + p4];
                    acc.x += (bf2f(u0.x) + bf2f(u1.x)) + (bf2f(u2.x) + bf2f(u3.x));
                    acc.y += (bf2f(u0.y) + bf2f(u1.y)) + (bf2f(u2.y) + bf2f(u3.y));
                    acc.z += (bf2f(u0.z) + bf2f(u1.z)) + (bf2f(u2.z) + bf2f(u3.z));
                    acc.w += (bf2f(u0.w) + bf2f(u1.w)) + (bf2f(u2.w) + bf2f(u3.w));
                }
                for (; e < m; e += 4) {
                    int sl = e + grp;
                    int o = __shfl(myoff, sl);
                    if (sl < m) {
                        ushort4 uu = *(const ushort4*)&hs2[(size_t)o + p4];
                        acc.x += bf2f(uu.x); acc.y += bf2f(uu.y);
                        acc.z += bf2f(uu.z); acc.w += bf2f(uu.w);
                    }
                }
            }
            acc.x += __shfl_xor(acc.x, 16); acc.y += __shfl_xor(acc.y, 16);
            acc.z += __shfl_xor(acc.z, 16); acc.w += __shfl_xor(acc.w, 16);
            acc.x += __shfl_xor(acc.x, 32); acc.y += __shfl_xor(acc.y, 32);
            acc.z += __shfl_xor(acc.z, 32); acc.w += __shfl_xor(acc.w, 32);
            if (grp == 0) {
                float dv = dinv[node];
                float vv[4] = {acc.x, acc.y, acc.z, acc.w};
#pragma unroll
                for (int j = 0; j < 4; j++) {
                    int f = p4 + j;
                    if (f < F2) out[(size_t)node * F2 + f] = vv[j] * dv + b2[f];
                }
            }
        }
    }
}

extern "C" void kernel_launch(void* const* d_in, const int* in_sizes, int n_in,
                              void* d_out, int out_size, void* d_ws, size_t ws_size,
                              hipStream_t stream) {
    const float* x  = (const float*)d_in[0];
    const int*   ei = (const int*)d_in[1];
    const float* W1 = (const float*)d_in[2];
    const float* b1 = (const float*)d_in[3];
    const float* W2 = (const float*)d_in[4];
    const float* b2 = (const float*)d_in[5];
    float* out = (float*)d_out;

    const int n = in_sizes[0] / FIN;   // 100000
    const int E = in_sizes[1] / 2;     // 1600000
    const int* src = ei;
    const int* dst = ei + E;
    const int nbuck   = (n + 255) >> BSH;              // 391
    const int nchunks = (E + CHUNK_P - 1) / CHUNK_P;   // 391
    const int nmm     = (n + MT - 1) / MT;             // 782
    const int nagg    = (n + 3) / 4;                   // 25000

    char* ws = (char*)d_ws;
    size_t off = 0;
    auto alloc = [&](size_t bytes) {
        void* p = ws + off;
        off = (off + bytes + 511) & ~(size_t)511;
        return p;
    };
    int*   gcur    = (int*)alloc((size_t)(NBMAX + 1) * 4);  // [NBMAX] = adj cursor
    int*   pairs   = (int*)alloc((size_t)nbuck * BCAP * 4); // ~9.6 MB
    int*   adj     = (int*)alloc((size_t)E * 4);
    int2*  rowinfo = (int2*)alloc((size_t)n * 8);
    float* dinv    = (float*)alloc((size_t)n * 4);
    unsigned short* hs1 = (unsigned short*)alloc((size_t)n * FP * 2);
    unsigned short* hs2 = (unsigned short*)alloc((size_t)n * FP * 2);
    unsigned short* h1b = (unsigned short*)alloc((size_t)n * FP * 2);

    // co-resident grid from occupancy (host-side query; capture-safe)
    int maxB = 0;
    hipOccupancyMaxActiveBlocksPerMultiprocessor(&maxB, (const void*)k_all, 256, 0);
    if (maxB < 1) maxB = 1;
    int grid = maxB * 256;                 // 256 CUs on MI355X
    if (grid > nagg) grid = nagg;          // no phase needs more
    if (grid < 3) grid = 3;                // phase-0 zeroing needs >=513 threads

    int n_ = n, E_ = E, nchunks_ = nchunks, nmm_ = nmm, nbuck_ = nbuck, nagg_ = nagg;
    void* args[] = {
        (void*)&src, (void*)&dst, (void*)&x, (void*)&W1, (void*)&b1,
        (void*)&W2, (void*)&b2, (void*)&out,
        (void*)&gcur, (void*)&pairs, (void*)&adj, (void*)&rowinfo, (void*)&dinv,
        (void*)&hs1, (void*)&hs2, (void*)&h1b,
        (void*)&n_, (void*)&E_, (void*)&nchunks_, (void*)&nmm_,
        (void*)&nbuck_, (void*)&nagg_
    };
    hipLaunchCooperativeKernel((const void*)k_all, dim3(grid), dim3(256),
                               args, 0, stream);
}

// Round 13
// 287.601 us; speedup vs baseline: 3.4137x; 3.4137x over previous
//
#include <hip/hip_runtime.h>

// GCN 2-layer forward. CSR-gather, bf16 payloads (stride-64, 128 B rows),
// 4-edges-per-gather aggregation. hs1 = x@W1 (unscaled -> mm1 independent of
// CSR build, fused with part); k_build pre-scales hs1 by dinv in its tail.
// Pipeline (5 dispatches): memset -> partmm1 -> build(+scale) -> agg1 ->
// mm2 -> agg2.

#define FIN 128
#define F1  64
#define F2  41
#define FP  64     // payload row stride (bf16 elems): 128 B, 2 lines, aligned

#define BSH    8                 // bucket = dst >> 8 (256 nodes/bucket)
#define BCAP   6144              // per-bucket edge window (mean 4096, >30 sigma)
#define NBMAX  512               // max buckets (n <= 131072)
#define CHUNK_P 4096             // edges per part block (16/thread)

#define MT 128                   // GEMM M-tile
#define KC 16                    // GEMM K-chunk

__device__ __forceinline__ unsigned short f2bf(float f) {
    unsigned u = __builtin_bit_cast(unsigned, f);
    u += 0x7FFFu + ((u >> 16) & 1u);           // RNE
    return (unsigned short)(u >> 16);
}
__device__ __forceinline__ float bf2f(unsigned short h) {
    unsigned u = ((unsigned)h) << 16;
    return __builtin_bit_cast(float, u);
}

// ---- fused: blocks [0,nchunks) = edge partition; rest = layer-1 GEMM -------
__global__ __launch_bounds__(256) void k_partmm1(
    const int* __restrict__ src, const int* __restrict__ dst,
    int* __restrict__ gcur, int* __restrict__ pairs, int E, int nchunks,
    const float* __restrict__ x, const float* __restrict__ W1,
    unsigned short* __restrict__ hs, int n) {
    __shared__ alignas(16) char smem[40960];
    int tid = threadIdx.x;
    if ((int)blockIdx.x < nchunks) {
        // ---------------- PART ----------------
        int* hist = (int*)smem;            // NBMAX
        int* gsh  = hist + NBMAX;          // NBMAX
        int* lex  = gsh + NBMAX;           // 256
        int* stot = lex + 256;             // 1 (+3 pad)
        int* limg = stot + 4;              // CHUNK_P (16 KB)
        int* lsh  = limg + CHUNK_P;        // CHUNK_P (16 KB)
        int e0  = blockIdx.x * CHUNK_P;
        int ds[CHUNK_P / 256], ss[CHUNK_P / 256];
#pragma unroll
        for (int j = 0; j < CHUNK_P / 256; j++) {
            int e = e0 + j * 256 + tid;
            if (e < E) { ds[j] = dst[e]; ss[j] = src[e]; } else ds[j] = -1;
        }
        hist[tid] = 0; hist[tid + 256] = 0;
        __syncthreads();
#pragma unroll
        for (int j = 0; j < CHUNK_P / 256; j++)
            if (ds[j] >= 0) atomicAdd(&hist[ds[j] >> BSH], 1);
        __syncthreads();
        int b0 = 2 * tid, b1 = 2 * tid + 1;
        int c0 = hist[b0], c1 = hist[b1];
        int s  = c0 + c1;
        lex[tid] = s;
        __syncthreads();
        for (int off = 1; off < 256; off <<= 1) {
            int v = lex[tid];
            int a = (tid >= off) ? lex[tid - off] : 0;
            __syncthreads();
            lex[tid] = v + a;
            __syncthreads();
        }
        int incl = lex[tid];
        if (tid == 255) stot[0] = incl;
        int ex = incl - s;
        int g0 = c0 ? atomicAdd(&gcur[b0], c0) : 0;
        int g1 = c1 ? atomicAdd(&gcur[b1], c1) : 0;
        hist[b0] = ex; hist[b1] = ex + c0;
        gsh[b0]  = b0 * BCAP + g0 - ex;
        gsh[b1]  = b1 * BCAP + g1 - (ex + c0);
        __syncthreads();
#pragma unroll
        for (int j = 0; j < CHUNK_P / 256; j++) {
            if (ds[j] >= 0) {
                int b = ds[j] >> BSH;
                int p = atomicAdd(&hist[b], 1);
                limg[p] = (ss[j] << BSH) | (ds[j] & 255);
                lsh[p]  = gsh[b];
            }
        }
        __syncthreads();
        int tot = stot[0];
        for (int k = tid; k < tot; k += 256)
            pairs[k + lsh[k]] = limg[k];
    } else {
        // ---------------- MM1: hs1 = bf16(x @ W1), UNSCALED ----------------
        float* Ws = (float*)smem;                        // 32 KB (full W1)
        float (*As)[MT] = (float(*)[MT])(smem + FIN * F1 * 4);  // 8 KB
        int n0 = ((int)blockIdx.x - nchunks) * MT;
#pragma unroll
        for (int j = 0; j < 8; j++) {
            int f = j * 256 + tid;
            ((float4*)Ws)[f] = ((const float4*)W1)[f];
        }
        int m0 = (tid & 15) * 8;
        int c0 = (tid >> 4) * 4;
        int m_l = tid & 127;
        int kh  = (tid >> 7) * 8;
        bool mvalid = (n0 + m_l) < n;
        const float* xrow = x + (size_t)(n0 + m_l) * FIN + kh;
        float acc[8][4] = {};
        for (int kc = 0; kc < FIN; kc += KC) {
            __syncthreads();
            float4 v0 = mvalid ? *(const float4*)(xrow + kc)     : float4{0.f,0.f,0.f,0.f};
            float4 v1 = mvalid ? *(const float4*)(xrow + kc + 4) : float4{0.f,0.f,0.f,0.f};
            As[kh + 0][m_l] = v0.x; As[kh + 1][m_l] = v0.y;
            As[kh + 2][m_l] = v0.z; As[kh + 3][m_l] = v0.w;
            As[kh + 4][m_l] = v1.x; As[kh + 5][m_l] = v1.y;
            As[kh + 6][m_l] = v1.z; As[kh + 7][m_l] = v1.w;
            __syncthreads();
#pragma unroll
            for (int k = 0; k < KC; k++) {
                float4 a0 = *(const float4*)&As[k][m0];
                float4 a1 = *(const float4*)&As[k][m0 + 4];
                float4 w  = *(const float4*)&Ws[(kc + k) * F1 + c0];
                float a[8] = {a0.x, a0.y, a0.z, a0.w, a1.x, a1.y, a1.z, a1.w};
#pragma unroll
                for (int i = 0; i < 8; i++) {
                    acc[i][0] += a[i] * w.x;
                    acc[i][1] += a[i] * w.y;
                    acc[i][2] += a[i] * w.z;
                    acc[i][3] += a[i] * w.w;
                }
            }
        }
#pragma unroll
        for (int i = 0; i < 8; i++) {
            int node = n0 + m0 + i;
            if (node < n) {
                ushort4 o = { f2bf(acc[i][0]), f2bf(acc[i][1]),
                              f2bf(acc[i][2]), f2bf(acc[i][3]) };
                *(ushort4*)&hs[((size_t)node << 6) + c0] = o;
            }
        }
    }
}

// ---- pass 2: per-bucket CSR build + tail-scale hs1 by dinv -----------------
__global__ __launch_bounds__(256) void k_build(
    const int* __restrict__ gcur, const int* __restrict__ pairs,
    int* __restrict__ adjcur, int* __restrict__ adj,
    int2* __restrict__ rowinfo, float* __restrict__ dinv,
    unsigned short* __restrict__ hs1, int n) {
    __shared__ int lcnt[256];
    __shared__ int lex[256];
    __shared__ int lcur[256];
    __shared__ int ladj[BCAP];
    __shared__ float ldv[256];
    __shared__ int sbase;
    int tid = threadIdx.x;
    int b   = blockIdx.x;
    int cntb  = gcur[b]; if (cntb > BCAP) cntb = BCAP;
    int node0 = b << BSH;
    const int* pb = pairs + (size_t)b * BCAP;

    if (tid == 0) sbase = atomicAdd(adjcur, cntb);
    lcnt[tid] = 0;
    __syncthreads();
    for (int k = tid; k < cntb; k += 256) atomicAdd(&lcnt[pb[k] & 255], 1);
    __syncthreads();
    int own = lcnt[tid];
    lex[tid] = own;
    __syncthreads();
    for (int off = 1; off < 256; off <<= 1) {
        int val = lex[tid];
        int add = (tid >= off) ? lex[tid - off] : 0;
        __syncthreads();
        lex[tid] = val + add;
        __syncthreads();
    }
    int excl = lex[tid] - own;
    __syncthreads();
    lcur[tid] = excl;
    float dvn = rsqrtf((float)own + 1.0f);
    ldv[tid]  = dvn;
    __syncthreads();
    for (int k = tid; k < cntb; k += 256) {
        int pk  = pb[k];
        int pos = atomicAdd(&lcur[pk & 255], 1);
        ladj[pos] = pk >> BSH;
    }
    __syncthreads();
    int base = sbase;
    for (int k = tid; k < cntb; k += 256) adj[base + k] = ladj[k];
    int node = node0 + tid;
    if (node < n) {
        rowinfo[node] = make_int2(base + excl, own);
        dinv[node]    = dvn;
    }
    // ---- tail: hs1[node] *= dinv[node] for this bucket's 256 nodes --------
    // 256 rows x 128 B = 2048 ushort8 units; coalesced 16 B per thread.
    for (int u = tid; u < 2048; u += 256) {
        int nd = node0 + (u >> 3);
        if (nd >= n) break;
        float dv = ldv[u >> 3];
        ushort4* p = (ushort4*)&hs1[((size_t)nd << 6) + (u & 7) * 8];
        ushort4 a = p[0], c = p[1];
        a.x = f2bf(bf2f(a.x) * dv); a.y = f2bf(bf2f(a.y) * dv);
        a.z = f2bf(bf2f(a.z) * dv); a.w = f2bf(bf2f(a.w) * dv);
        c.x = f2bf(bf2f(c.x) * dv); c.y = f2bf(bf2f(c.y) * dv);
        c.z = f2bf(bf2f(c.z) * dv); c.w = f2bf(bf2f(c.w) * dv);
        p[0] = a; p[1] = c;
    }
}

// ---- layer 1 aggregate: h1 = bf16(relu(dinv*(gather+self) + b1)) -----------
// hs pre-scaled by dinv[src]; self term = hs[node] (already dinv[node]-scaled).
__global__ __launch_bounds__(256) void k_agg1(
    const int2* __restrict__ rowinfo, const int* __restrict__ adj,
    const unsigned short* __restrict__ hs, const float* __restrict__ dinv,
    const float* __restrict__ b1, unsigned short* __restrict__ h1b, int n, int E) {
    int node = blockIdx.x * 4 + (threadIdx.x >> 6);
    if (node >= n) return;
    int lane = threadIdx.x & 63;
    int grp  = lane >> 4;
    int p4   = (lane & 15) * 4;
    int2 ri = rowinfo[node];
    int beg = ri.x, deg = ri.y;
    float4 acc = {0.f, 0.f, 0.f, 0.f};
    if (grp == 0) {                  // self-loop (pre-scaled)
        ushort4 u = *(const ushort4*)&hs[((size_t)node << 6) + p4];
        acc.x = bf2f(u.x); acc.y = bf2f(u.y); acc.z = bf2f(u.z); acc.w = bf2f(u.w);
    }
    for (int base = 0; base < deg; base += 64) {
        int m = deg - base; if (m > 64) m = 64;
        int idx = beg + base + lane;
        int myoff = adj[idx < E ? idx : 0] << 6;
        int e = 0;
        for (; e + 16 <= m; e += 16) {
            int o0 = __shfl(myoff, e + grp),      o1 = __shfl(myoff, e + 4 + grp);
            int o2 = __shfl(myoff, e + 8 + grp),  o3 = __shfl(myoff, e + 12 + grp);
            ushort4 u0 = *(const ushort4*)&hs[(size_t)o0 + p4];
            ushort4 u1 = *(const ushort4*)&hs[(size_t)o1 + p4];
            ushort4 u2 = *(const ushort4*)&hs[(size_t)o2 + p4];
            ushort4 u3 = *(const ushort4*)&hs[(size_t)o3 + p4];
            acc.x += (bf2f(u0.x) + bf2f(u1.x)) + (bf2f(u2.x) + bf2f(u3.x));
            acc.y += (bf2f(u0.y) + bf2f(u1.y)) + (bf2f(u2.y) + bf2f(u3.y));
            acc.z += (bf2f(u0.z) + bf2f(u1.z)) + (bf2f(u2.z) + bf2f(u3.z));
            acc.w += (bf2f(u0.w) + bf2f(u1.w)) + (bf2f(u2.w) + bf2f(u3.w));
        }
        for (; e < m; e += 4) {
            int sl = e + grp;
            int o = __shfl(myoff, sl);
            if (sl < m) {
                ushort4 u = *(const ushort4*)&hs[(size_t)o + p4];
                acc.x += bf2f(u.x); acc.y += bf2f(u.y);
                acc.z += bf2f(u.z); acc.w += bf2f(u.w);
            }
        }
    }
    acc.x += __shfl_xor(acc.x, 16); acc.y += __shfl_xor(acc.y, 16);
    acc.z += __shfl_xor(acc.z, 16); acc.w += __shfl_xor(acc.w, 16);
    acc.x += __shfl_xor(acc.x, 32); acc.y += __shfl_xor(acc.y, 32);
    acc.z += __shfl_xor(acc.z, 32); acc.w += __shfl_xor(acc.w, 32);
    if (grp == 0) {
        float dvn = dinv[node];
        float4 bg = *(const float4*)&b1[p4];
        float vx = acc.x * dvn + bg.x; vx = vx > 0.f ? vx : 0.f;
        float vy = acc.y * dvn + bg.y; vy = vy > 0.f ? vy : 0.f;
        float vz = acc.z * dvn + bg.z; vz = vz > 0.f ? vz : 0.f;
        float vw = acc.w * dvn + bg.w; vw = vw > 0.f ? vw : 0.f;
        ushort4 o = { f2bf(vx), f2bf(vy), f2bf(vz), f2bf(vw) };
        *(ushort4*)&h1b[((size_t)node << 6) + p4] = o;
    }
}

// ---- layer 2 GEMM (tiled): hs2 = bf16( (h1 @ W2) * dinv ), stride 64 -------
__global__ __launch_bounds__(256) void k_mm2(
    const unsigned short* __restrict__ h1b, const float* __restrict__ W2,
    const float* __restrict__ dinv, unsigned short* __restrict__ hs2, int n) {
    __shared__ float Ws[F1 * FP];    // 16 KB padded (cols 41..63 = 0)
    __shared__ float As[KC][MT];
    int t  = threadIdx.x;
    int n0 = blockIdx.x * MT;
    for (int idx = t; idx < F1 * FP; idx += 256) {
        int k = idx >> 6, c = idx & 63;
        Ws[idx] = (c < F2) ? W2[k * F2 + c] : 0.f;
    }
    int m0 = (t & 15) * 8;
    int c0 = (t >> 4) * 4;
    int m_l = t & 127;
    int kh  = (t >> 7) * 8;
    bool mvalid = (n0 + m_l) < n;
    const unsigned short* hrow = h1b + ((size_t)(n0 + m_l) << 6) + kh;
    float acc[8][4] = {};
    for (int kc = 0; kc < F1; kc += KC) {
        __syncthreads();
        ushort4 u0 = mvalid ? *(const ushort4*)(hrow + kc)     : ushort4{0,0,0,0};
        ushort4 u1 = mvalid ? *(const ushort4*)(hrow + kc + 4) : ushort4{0,0,0,0};
        As[kh + 0][m_l] = bf2f(u0.x); As[kh + 1][m_l] = bf2f(u0.y);
        As[kh + 2][m_l] = bf2f(u0.z); As[kh + 3][m_l] = bf2f(u0.w);
        As[kh + 4][m_l] = bf2f(u1.x); As[kh + 5][m_l] = bf2f(u1.y);
        As[kh + 6][m_l] = bf2f(u1.z); As[kh + 7][m_l] = bf2f(u1.w);
        __syncthreads();
#pragma unroll
        for (int k = 0; k < KC; k++) {
            float4 a0 = *(const float4*)&As[k][m0];
            float4 a1 = *(const float4*)&As[k][m0 + 4];
            float4 w  = *(const float4*)&Ws[(kc + k) * FP + c0];
            float a[8] = {a0.x, a0.y, a0.z, a0.w, a1.x, a1.y, a1.z, a1.w};
#pragma unroll
            for (int i = 0; i < 8; i++) {
                acc[i][0] += a[i] * w.x;
                acc[i][1] += a[i] * w.y;
                acc[i][2] += a[i] * w.z;
                acc[i][3] += a[i] * w.w;
            }
        }
    }
#pragma unroll
    for (int i = 0; i < 8; i++) {
        int node = n0 + m0 + i;
        if (node < n) {
            float dv = dinv[node];
            ushort4 o = { f2bf(acc[i][0] * dv), f2bf(acc[i][1] * dv),
                          f2bf(acc[i][2] * dv), f2bf(acc[i][3] * dv) };
            *(ushort4*)&hs2[((size_t)node << 6) + c0] = o;
        }
    }
}

// ---- layer 2 aggregate: out = dinv*(gather+self) + b2 ----------------------
__global__ __launch_bounds__(256) void k_agg2(
    const int2* __restrict__ rowinfo, const int* __restrict__ adj,
    const unsigned short* __restrict__ hs2, const float* __restrict__ dinv,
    const float* __restrict__ b2, float* __restrict__ out, int n, int E) {
    int node = blockIdx.x * 4 + (threadIdx.x >> 6);
    if (node >= n) return;
    int lane = threadIdx.x & 63;
    int grp  = lane >> 4;
    int p4   = (lane & 15) * 4;
    int2 ri = rowinfo[node];
    int beg = ri.x, deg = ri.y;
    float4 acc = {0.f, 0.f, 0.f, 0.f};
    if (grp == 0) {
        ushort4 u = *(const ushort4*)&hs2[((size_t)node << 6) + p4];
        acc.x = bf2f(u.x); acc.y = bf2f(u.y); acc.z = bf2f(u.z); acc.w = bf2f(u.w);
    }
    for (int base = 0; base < deg; base += 64) {
        int m = deg - base; if (m > 64) m = 64;
        int idx = beg + base + lane;
        int myoff = adj[idx < E ? idx : 0] << 6;
        int e = 0;
        for (; e + 16 <= m; e += 16) {
            int o0 = __shfl(myoff, e + grp),      o1 = __shfl(myoff, e + 4 + grp);
            int o2 = __shfl(myoff, e + 8 + grp),  o3 = __shfl(myoff, e + 12 + grp);
            ushort4 u0 = *(const ushort4*)&hs2[(size_t)o0 + p4];
            ushort4 u1 = *(const ushort4*)&hs2[(size_t)o1 + p4];
            ushort4 u2 = *(const ushort4*)&hs2[(size_t)o2 + p4];
            ushort4 u3 = *(const ushort4*)&hs2[(size_t)o3 + p4];
            acc.x += (bf2f(u0.x) + bf2f(u1.x)) + (bf2f(u2.x) + bf2f(u3.x));
            acc.y += (bf2f(u0.y) + bf2f(u1.y)) + (bf2f(u2.y) + bf2f(u3.y));
            acc.z += (bf2f(u0.z) + bf2f(u1.z)) + (bf2f(u2.z) + bf2f(u3.z));
            acc.w += (bf2f(u0.w) + bf2f(u1.w)) + (bf2f(u2.w) + bf2f(u3.w));
        }
        for (; e < m; e += 4) {
            int sl = e + grp;
            int o = __shfl(myoff, sl);
            if (sl < m) {
                ushort4 u = *(const ushort4*)&hs2[(size_t)o + p4];
                acc.x += bf2f(u.x); acc.y += bf2f(u.y);
                acc.z += bf2f(u.z); acc.w += bf2f(u.w);
            }
        }
    }
    acc.x += __shfl_xor(acc.x, 16); acc.y += __shfl_xor(acc.y, 16);
    acc.z += __shfl_xor(acc.z, 16); acc.w += __shfl_xor(acc.w, 16);
    acc.x += __shfl_xor(acc.x, 32); acc.y += __shfl_xor(acc.y, 32);
    acc.z += __shfl_xor(acc.z, 32); acc.w += __shfl_xor(acc.w, 32);
    if (grp == 0) {
        float dv = dinv[node];
        float vv[4] = {acc.x, acc.y, acc.z, acc.w};
#pragma unroll
        for (int j = 0; j < 4; j++) {
            int f = p4 + j;
            if (f < F2) out[(size_t)node * F2 + f] = vv[j] * dv + b2[f];
        }
    }
}

extern "C" void kernel_launch(void* const* d_in, const int* in_sizes, int n_in,
                              void* d_out, int out_size, void* d_ws, size_t ws_size,
                              hipStream_t stream) {
    const float* x  = (const float*)d_in[0];
    const int*   ei = (const int*)d_in[1];
    const float* W1 = (const float*)d_in[2];
    const float* b1 = (const float*)d_in[3];
    const float* W2 = (const float*)d_in[4];
    const float* b2 = (const float*)d_in[5];
    float* out = (float*)d_out;

    const int n = in_sizes[0] / FIN;   // 100000
    const int E = in_sizes[1] / 2;     // 1600000
    const int* src = ei;
    const int* dst = ei + E;
    const int nbuck   = (n + 255) >> BSH;              // 391 (<= NBMAX)
    const int nchunks = (E + CHUNK_P - 1) / CHUNK_P;   // 391
    const int nmm     = (n + MT - 1) / MT;             // 782
    const int nagg    = (n + 3) / 4;                   // 25000

    char* ws = (char*)d_ws;
    size_t off = 0;
    auto alloc = [&](size_t bytes) {
        void* p = ws + off;
        off = (off + bytes + 511) & ~(size_t)511;
        return p;
    };
    int*   gcur    = (int*)alloc((size_t)(NBMAX + 1) * 4);  // [NBMAX] = adj cursor
    int*   pairs   = (int*)alloc((size_t)nbuck * BCAP * 4); // ~9.6 MB
    int*   adj     = (int*)alloc((size_t)E * 4);
    int2*  rowinfo = (int2*)alloc((size_t)n * 8);
    float* dinv    = (float*)alloc((size_t)n * 4);
    unsigned short* hs1 = (unsigned short*)alloc((size_t)n * FP * 2);
    unsigned short* hs2 = (unsigned short*)alloc((size_t)n * FP * 2);
    unsigned short* h1b = (unsigned short*)alloc((size_t)n * FP * 2);

    hipMemsetAsync(gcur, 0, (size_t)(NBMAX + 1) * 4, stream);
    k_partmm1<<<nchunks + nmm, 256, 0, stream>>>(src, dst, gcur, pairs, E, nchunks,
                                                 x, W1, hs1, n);
    k_build<<<nbuck, 256, 0, stream>>>(gcur, pairs, gcur + NBMAX, adj, rowinfo,
                                       dinv, hs1, n);
    k_agg1<<<nagg, 256, 0, stream>>>(rowinfo, adj, hs1, dinv, b1, h1b, n, E);
    k_mm2<<<nmm, 256, 0, stream>>>(h1b, W2, dinv, hs2, n);
    k_agg2<<<nagg, 256, 0, stream>>>(rowinfo, adj, hs2, dinv, b2, out, n, E);
}

// Round 14
// 285.955 us; speedup vs baseline: 3.4334x; 1.0058x over previous
//
#include <hip/hip_runtime.h>

// GCN 2-layer forward. CSR-gather, bf16 payloads (stride-64, 128 B rows),
// 4-edges-per-gather aggregation. hs1 = x@W1 (unscaled; mm1 fused with part,
// build pre-scales hs1 by dinv). LDS union 29.2 KB (part: ushort bucket-id
// slots; mm1: W1 staged bf16) -> 5 blocks/CU on the fused kernel.
// Pipeline (5 dispatches): memset -> partmm1 -> build(+scale) -> agg1 ->
// mm2 -> agg2.

#define FIN 128
#define F1  64
#define F2  41
#define FP  64     // payload row stride (bf16 elems): 128 B, 2 lines, aligned

#define BSH    8                 // bucket = dst >> 8 (256 nodes/bucket)
#define BCAP   6144              // per-bucket edge window (mean 4096, >30 sigma)
#define NBMAX  512               // max buckets (n <= 131072)
#define CHUNK_P 4096             // edges per part block (16/thread)

#define MT 128                   // GEMM M-tile
#define KC 16                    // GEMM K-chunk

#define SMEM_BYTES 29952         // union: part 29.2 KB / mm1 24.6 KB

__device__ __forceinline__ unsigned short f2bf(float f) {
    unsigned u = __builtin_bit_cast(unsigned, f);
    u += 0x7FFFu + ((u >> 16) & 1u);           // RNE
    return (unsigned short)(u >> 16);
}
__device__ __forceinline__ float bf2f(unsigned short h) {
    unsigned u = ((unsigned)h) << 16;
    return __builtin_bit_cast(float, u);
}

// ---- fused: blocks [0,nchunks) = edge partition; rest = layer-1 GEMM -------
__global__ __launch_bounds__(256) void k_partmm1(
    const int* __restrict__ src, const int* __restrict__ dst,
    int* __restrict__ gcur, int* __restrict__ pairs, int E, int nchunks,
    const float* __restrict__ x, const float* __restrict__ W1,
    unsigned short* __restrict__ hs, int n) {
    __shared__ alignas(16) char smem[SMEM_BYTES];
    int tid = threadIdx.x;
    if ((int)blockIdx.x < nchunks) {
        // ---------------- PART (29.2 KB) ----------------
        int* hist = (int*)smem;            // NBMAX (2 KB)
        int* gsh  = hist + NBMAX;          // NBMAX (2 KB)
        int* lex  = gsh + NBMAX;           // 256 (1 KB)
        int* stot = lex + 256;             // 4
        int* limg = stot + 4;              // CHUNK_P ints (16 KB)
        unsigned short* bid = (unsigned short*)(limg + CHUNK_P);  // 8 KB
        int e0  = blockIdx.x * CHUNK_P;
        int ds[CHUNK_P / 256], ss[CHUNK_P / 256];
#pragma unroll
        for (int j = 0; j < CHUNK_P / 256; j++) {
            int e = e0 + j * 256 + tid;
            if (e < E) { ds[j] = dst[e]; ss[j] = src[e]; } else ds[j] = -1;
        }
        hist[tid] = 0; hist[tid + 256] = 0;
        __syncthreads();
#pragma unroll
        for (int j = 0; j < CHUNK_P / 256; j++)
            if (ds[j] >= 0) atomicAdd(&hist[ds[j] >> BSH], 1);
        __syncthreads();
        int b0 = 2 * tid, b1 = 2 * tid + 1;
        int c0 = hist[b0], c1 = hist[b1];
        int s  = c0 + c1;
        lex[tid] = s;
        __syncthreads();
        for (int off = 1; off < 256; off <<= 1) {
            int v = lex[tid];
            int a = (tid >= off) ? lex[tid - off] : 0;
            __syncthreads();
            lex[tid] = v + a;
            __syncthreads();
        }
        int incl = lex[tid];
        if (tid == 255) stot[0] = incl;
        int ex = incl - s;
        int g0 = c0 ? atomicAdd(&gcur[b0], c0) : 0;
        int g1 = c1 ? atomicAdd(&gcur[b1], c1) : 0;
        hist[b0] = ex; hist[b1] = ex + c0;
        gsh[b0]  = b0 * BCAP + g0 - ex;
        gsh[b1]  = b1 * BCAP + g1 - (ex + c0);
        __syncthreads();
#pragma unroll
        for (int j = 0; j < CHUNK_P / 256; j++) {
            if (ds[j] >= 0) {
                int b = ds[j] >> BSH;
                int p = atomicAdd(&hist[b], 1);
                limg[p] = (ss[j] << BSH) | (ds[j] & 255);
                bid[p]  = (unsigned short)b;
            }
        }
        __syncthreads();
        int tot = stot[0];
        for (int k = tid; k < tot; k += 256)
            pairs[k + gsh[bid[k]]] = limg[k];
    } else {
        // ---------------- MM1: hs1 = bf16(x @ W1), UNSCALED (24.6 KB) -------
        unsigned short* Ws = (unsigned short*)smem;      // 16 KB, W1 as bf16
        float (*As)[MT] = (float(*)[MT])(smem + FIN * F1 * 2);  // 8 KB
        int n0 = ((int)blockIdx.x - nchunks) * MT;
#pragma unroll
        for (int j = 0; j < 8; j++) {
            int f = j * 256 + tid;                       // float4 index (2048)
            float4 w4 = ((const float4*)W1)[f];
            ushort4 o = { f2bf(w4.x), f2bf(w4.y), f2bf(w4.z), f2bf(w4.w) };
            ((ushort4*)Ws)[f] = o;
        }
        int m0 = (tid & 15) * 8;
        int c0 = (tid >> 4) * 4;
        int m_l = tid & 127;
        int kh  = (tid >> 7) * 8;
        bool mvalid = (n0 + m_l) < n;
        const float* xrow = x + (size_t)(n0 + m_l) * FIN + kh;
        float acc[8][4] = {};
        for (int kc = 0; kc < FIN; kc += KC) {
            __syncthreads();
            float4 v0 = mvalid ? *(const float4*)(xrow + kc)     : float4{0.f,0.f,0.f,0.f};
            float4 v1 = mvalid ? *(const float4*)(xrow + kc + 4) : float4{0.f,0.f,0.f,0.f};
            As[kh + 0][m_l] = v0.x; As[kh + 1][m_l] = v0.y;
            As[kh + 2][m_l] = v0.z; As[kh + 3][m_l] = v0.w;
            As[kh + 4][m_l] = v1.x; As[kh + 5][m_l] = v1.y;
            As[kh + 6][m_l] = v1.z; As[kh + 7][m_l] = v1.w;
            __syncthreads();
#pragma unroll
            for (int k = 0; k < KC; k++) {
                float4 a0 = *(const float4*)&As[k][m0];
                float4 a1 = *(const float4*)&As[k][m0 + 4];
                ushort4 wq = *(const ushort4*)&Ws[(kc + k) * F1 + c0];
                float wx = bf2f(wq.x), wy = bf2f(wq.y);
                float wz = bf2f(wq.z), ww = bf2f(wq.w);
                float a[8] = {a0.x, a0.y, a0.z, a0.w, a1.x, a1.y, a1.z, a1.w};
#pragma unroll
                for (int i = 0; i < 8; i++) {
                    acc[i][0] += a[i] * wx;
                    acc[i][1] += a[i] * wy;
                    acc[i][2] += a[i] * wz;
                    acc[i][3] += a[i] * ww;
                }
            }
        }
#pragma unroll
        for (int i = 0; i < 8; i++) {
            int node = n0 + m0 + i;
            if (node < n) {
                ushort4 o = { f2bf(acc[i][0]), f2bf(acc[i][1]),
                              f2bf(acc[i][2]), f2bf(acc[i][3]) };
                *(ushort4*)&hs[((size_t)node << 6) + c0] = o;
            }
        }
    }
}

// ---- pass 2: per-bucket CSR build + tail-scale hs1 by dinv -----------------
__global__ __launch_bounds__(256) void k_build(
    const int* __restrict__ gcur, const int* __restrict__ pairs,
    int* __restrict__ adjcur, int* __restrict__ adj,
    int2* __restrict__ rowinfo, float* __restrict__ dinv,
    unsigned short* __restrict__ hs1, int n) {
    __shared__ int lcnt[256];
    __shared__ int lex[256];
    __shared__ int lcur[256];
    __shared__ int ladj[BCAP];
    __shared__ float ldv[256];
    __shared__ int sbase;
    int tid = threadIdx.x;
    int b   = blockIdx.x;
    int cntb  = gcur[b]; if (cntb > BCAP) cntb = BCAP;
    int node0 = b << BSH;
    const int* pb = pairs + (size_t)b * BCAP;

    if (tid == 0) sbase = atomicAdd(adjcur, cntb);
    lcnt[tid] = 0;
    __syncthreads();
    for (int k = tid; k < cntb; k += 256) atomicAdd(&lcnt[pb[k] & 255], 1);
    __syncthreads();
    int own = lcnt[tid];
    lex[tid] = own;
    __syncthreads();
    for (int off = 1; off < 256; off <<= 1) {
        int val = lex[tid];
        int add = (tid >= off) ? lex[tid - off] : 0;
        __syncthreads();
        lex[tid] = val + add;
        __syncthreads();
    }
    int excl = lex[tid] - own;
    __syncthreads();
    lcur[tid] = excl;
    float dvn = rsqrtf((float)own + 1.0f);
    ldv[tid]  = dvn;
    __syncthreads();
    for (int k = tid; k < cntb; k += 256) {
        int pk  = pb[k];
        int pos = atomicAdd(&lcur[pk & 255], 1);
        ladj[pos] = pk >> BSH;
    }
    __syncthreads();
    int base = sbase;
    for (int k = tid; k < cntb; k += 256) adj[base + k] = ladj[k];
    int node = node0 + tid;
    if (node < n) {
        rowinfo[node] = make_int2(base + excl, own);
        dinv[node]    = dvn;
    }
    // ---- tail: hs1[node] *= dinv[node] for this bucket's 256 nodes --------
    for (int u = tid; u < 2048; u += 256) {
        int nd = node0 + (u >> 3);
        if (nd >= n) break;
        float dv = ldv[u >> 3];
        ushort4* p = (ushort4*)&hs1[((size_t)nd << 6) + (u & 7) * 8];
        ushort4 a = p[0], c = p[1];
        a.x = f2bf(bf2f(a.x) * dv); a.y = f2bf(bf2f(a.y) * dv);
        a.z = f2bf(bf2f(a.z) * dv); a.w = f2bf(bf2f(a.w) * dv);
        c.x = f2bf(bf2f(c.x) * dv); c.y = f2bf(bf2f(c.y) * dv);
        c.z = f2bf(bf2f(c.z) * dv); c.w = f2bf(bf2f(c.w) * dv);
        p[0] = a; p[1] = c;
    }
}

// ---- layer 1 aggregate: h1 = bf16(relu(dinv*(gather+self) + b1)) -----------
__global__ __launch_bounds__(256) void k_agg1(
    const int2* __restrict__ rowinfo, const int* __restrict__ adj,
    const unsigned short* __restrict__ hs, const float* __restrict__ dinv,
    const float* __restrict__ b1, unsigned short* __restrict__ h1b, int n, int E) {
    int node = blockIdx.x * 4 + (threadIdx.x >> 6);
    if (node >= n) return;
    int lane = threadIdx.x & 63;
    int grp  = lane >> 4;
    int p4   = (lane & 15) * 4;
    int2 ri = rowinfo[node];
    int beg = ri.x, deg = ri.y;
    float4 acc = {0.f, 0.f, 0.f, 0.f};
    if (grp == 0) {                  // self-loop (pre-scaled)
        ushort4 u = *(const ushort4*)&hs[((size_t)node << 6) + p4];
        acc.x = bf2f(u.x); acc.y = bf2f(u.y); acc.z = bf2f(u.z); acc.w = bf2f(u.w);
    }
    for (int base = 0; base < deg; base += 64) {
        int m = deg - base; if (m > 64) m = 64;
        int idx = beg + base + lane;
        int myoff = adj[idx < E ? idx : 0] << 6;
        int e = 0;
        for (; e + 16 <= m; e += 16) {
            int o0 = __shfl(myoff, e + grp),      o1 = __shfl(myoff, e + 4 + grp);
            int o2 = __shfl(myoff, e + 8 + grp),  o3 = __shfl(myoff, e + 12 + grp);
            ushort4 u0 = *(const ushort4*)&hs[(size_t)o0 + p4];
            ushort4 u1 = *(const ushort4*)&hs[(size_t)o1 + p4];
            ushort4 u2 = *(const ushort4*)&hs[(size_t)o2 + p4];
            ushort4 u3 = *(const ushort4*)&hs[(size_t)o3 + p4];
            acc.x += (bf2f(u0.x) + bf2f(u1.x)) + (bf2f(u2.x) + bf2f(u3.x));
            acc.y += (bf2f(u0.y) + bf2f(u1.y)) + (bf2f(u2.y) + bf2f(u3.y));
            acc.z += (bf2f(u0.z) + bf2f(u1.z)) + (bf2f(u2.z) + bf2f(u3.z));
            acc.w += (bf2f(u0.w) + bf2f(u1.w)) + (bf2f(u2.w) + bf2f(u3.w));
        }
        for (; e < m; e += 4) {
            int sl = e + grp;
            int o = __shfl(myoff, sl);
            if (sl < m) {
                ushort4 u = *(const ushort4*)&hs[(size_t)o + p4];
                acc.x += bf2f(u.x); acc.y += bf2f(u.y);
                acc.z += bf2f(u.z); acc.w += bf2f(u.w);
            }
        }
    }
    acc.x += __shfl_xor(acc.x, 16); acc.y += __shfl_xor(acc.y, 16);
    acc.z += __shfl_xor(acc.z, 16); acc.w += __shfl_xor(acc.w, 16);
    acc.x += __shfl_xor(acc.x, 32); acc.y += __shfl_xor(acc.y, 32);
    acc.z += __shfl_xor(acc.z, 32); acc.w += __shfl_xor(acc.w, 32);
    if (grp == 0) {
        float dvn = dinv[node];
        float4 bg = *(const float4*)&b1[p4];
        float vx = acc.x * dvn + bg.x; vx = vx > 0.f ? vx : 0.f;
        float vy = acc.y * dvn + bg.y; vy = vy > 0.f ? vy : 0.f;
        float vz = acc.z * dvn + bg.z; vz = vz > 0.f ? vz : 0.f;
        float vw = acc.w * dvn + bg.w; vw = vw > 0.f ? vw : 0.f;
        ushort4 o = { f2bf(vx), f2bf(vy), f2bf(vz), f2bf(vw) };
        *(ushort4*)&h1b[((size_t)node << 6) + p4] = o;
    }
}

// ---- layer 2 GEMM (tiled): hs2 = bf16( (h1 @ W2) * dinv ), stride 64 -------
__global__ __launch_bounds__(256) void k_mm2(
    const unsigned short* __restrict__ h1b, const float* __restrict__ W2,
    const float* __restrict__ dinv, unsigned short* __restrict__ hs2, int n) {
    __shared__ float Ws[F1 * FP];    // 16 KB padded (cols 41..63 = 0)
    __shared__ float As[KC][MT];
    int t  = threadIdx.x;
    int n0 = blockIdx.x * MT;
    for (int idx = t; idx < F1 * FP; idx += 256) {
        int k = idx >> 6, c = idx & 63;
        Ws[idx] = (c < F2) ? W2[k * F2 + c] : 0.f;
    }
    int m0 = (t & 15) * 8;
    int c0 = (t >> 4) * 4;
    int m_l = t & 127;
    int kh  = (t >> 7) * 8;
    bool mvalid = (n0 + m_l) < n;
    const unsigned short* hrow = h1b + ((size_t)(n0 + m_l) << 6) + kh;
    float acc[8][4] = {};
    for (int kc = 0; kc < F1; kc += KC) {
        __syncthreads();
        ushort4 u0 = mvalid ? *(const ushort4*)(hrow + kc)     : ushort4{0,0,0,0};
        ushort4 u1 = mvalid ? *(const ushort4*)(hrow + kc + 4) : ushort4{0,0,0,0};
        As[kh + 0][m_l] = bf2f(u0.x); As[kh + 1][m_l] = bf2f(u0.y);
        As[kh + 2][m_l] = bf2f(u0.z); As[kh + 3][m_l] = bf2f(u0.w);
        As[kh + 4][m_l] = bf2f(u1.x); As[kh + 5][m_l] = bf2f(u1.y);
        As[kh + 6][m_l] = bf2f(u1.z); As[kh + 7][m_l] = bf2f(u1.w);
        __syncthreads();
#pragma unroll
        for (int k = 0; k < KC; k++) {
            float4 a0 = *(const float4*)&As[k][m0];
            float4 a1 = *(const float4*)&As[k][m0 + 4];
            float4 w  = *(const float4*)&Ws[(kc + k) * FP + c0];
            float a[8] = {a0.x, a0.y, a0.z, a0.w, a1.x, a1.y, a1.z, a1.w};
#pragma unroll
            for (int i = 0; i < 8; i++) {
                acc[i][0] += a[i] * w.x;
                acc[i][1] += a[i] * w.y;
                acc[i][2] += a[i] * w.z;
                acc[i][3] += a[i] * w.w;
            }
        }
    }
#pragma unroll
    for (int i = 0; i < 8; i++) {
        int node = n0 + m0 + i;
        if (node < n) {
            float dv = dinv[node];
            ushort4 o = { f2bf(acc[i][0] * dv), f2bf(acc[i][1] * dv),
                          f2bf(acc[i][2] * dv), f2bf(acc[i][3] * dv) };
            *(ushort4*)&hs2[((size_t)node << 6) + c0] = o;
        }
    }
}

// ---- layer 2 aggregate: out = dinv*(gather+self) + b2 ----------------------
__global__ __launch_bounds__(256) void k_agg2(
    const int2* __restrict__ rowinfo, const int* __restrict__ adj,
    const unsigned short* __restrict__ hs2, const float* __restrict__ dinv,
    const float* __restrict__ b2, float* __restrict__ out, int n, int E) {
    int node = blockIdx.x * 4 + (threadIdx.x >> 6);
    if (node >= n) return;
    int lane = threadIdx.x & 63;
    int grp  = lane >> 4;
    int p4   = (lane & 15) * 4;
    int2 ri = rowinfo[node];
    int beg = ri.x, deg = ri.y;
    float4 acc = {0.f, 0.f, 0.f, 0.f};
    if (grp == 0) {
        ushort4 u = *(const ushort4*)&hs2[((size_t)node << 6) + p4];
        acc.x = bf2f(u.x); acc.y = bf2f(u.y); acc.z = bf2f(u.z); acc.w = bf2f(u.w);
    }
    for (int base = 0; base < deg; base += 64) {
        int m = deg - base; if (m > 64) m = 64;
        int idx = beg + base + lane;
        int myoff = adj[idx < E ? idx : 0] << 6;
        int e = 0;
        for (; e + 16 <= m; e += 16) {
            int o0 = __shfl(myoff, e + grp),      o1 = __shfl(myoff, e + 4 + grp);
            int o2 = __shfl(myoff, e + 8 + grp),  o3 = __shfl(myoff, e + 12 + grp);
            ushort4 u0 = *(const ushort4*)&hs2[(size_t)o0 + p4];
            ushort4 u1 = *(const ushort4*)&hs2[(size_t)o1 + p4];
            ushort4 u2 = *(const ushort4*)&hs2[(size_t)o2 + p4];
            ushort4 u3 = *(const ushort4*)&hs2[(size_t)o3 + p4];
            acc.x += (bf2f(u0.x) + bf2f(u1.x)) + (bf2f(u2.x) + bf2f(u3.x));
            acc.y += (bf2f(u0.y) + bf2f(u1.y)) + (bf2f(u2.y) + bf2f(u3.y));
            acc.z += (bf2f(u0.z) + bf2f(u1.z)) + (bf2f(u2.z) + bf2f(u3.z));
            acc.w += (bf2f(u0.w) + bf2f(u1.w)) + (bf2f(u2.w) + bf2f(u3.w));
        }
        for (; e < m; e += 4) {
            int sl = e + grp;
            int o = __shfl(myoff, sl);
            if (sl < m) {
                ushort4 u = *(const ushort4*)&hs2[(size_t)o + p4];
                acc.x += bf2f(u.x); acc.y += bf2f(u.y);
                acc.z += bf2f(u.z); acc.w += bf2f(u.w);
            }
        }
    }
    acc.x += __shfl_xor(acc.x, 16); acc.y += __shfl_xor(acc.y, 16);
    acc.z += __shfl_xor(acc.z, 16); acc.w += __shfl_xor(acc.w, 16);
    acc.x += __shfl_xor(acc.x, 32); acc.y += __shfl_xor(acc.y, 32);
    acc.z += __shfl_xor(acc.z, 32); acc.w += __shfl_xor(acc.w, 32);
    if (grp == 0) {
        float dv = dinv[node];
        float vv[4] = {acc.x, acc.y, acc.z, acc.w};
#pragma unroll
        for (int j = 0; j < 4; j++) {
            int f = p4 + j;
            if (f < F2) out[(size_t)node * F2 + f] = vv[j] * dv + b2[f];
        }
    }
}

extern "C" void kernel_launch(void* const* d_in, const int* in_sizes, int n_in,
                              void* d_out, int out_size, void* d_ws, size_t ws_size,
                              hipStream_t stream) {
    const float* x  = (const float*)d_in[0];
    const int*   ei = (const int*)d_in[1];
    const float* W1 = (const float*)d_in[2];
    const float* b1 = (const float*)d_in[3];
    const float* W2 = (const float*)d_in[4];
    const float* b2 = (const float*)d_in[5];
    float* out = (float*)d_out;

    const int n = in_sizes[0] / FIN;   // 100000
    const int E = in_sizes[1] / 2;     // 1600000
    const int* src = ei;
    const int* dst = ei + E;
    const int nbuck   = (n + 255) >> BSH;              // 391 (<= NBMAX)
    const int nchunks = (E + CHUNK_P - 1) / CHUNK_P;   // 391
    const int nmm     = (n + MT - 1) / MT;             // 782
    const int nagg    = (n + 3) / 4;                   // 25000

    char* ws = (char*)d_ws;
    size_t off = 0;
    auto alloc = [&](size_t bytes) {
        void* p = ws + off;
        off = (off + bytes + 511) & ~(size_t)511;
        return p;
    };
    int*   gcur    = (int*)alloc((size_t)(NBMAX + 1) * 4);  // [NBMAX] = adj cursor
    int*   pairs   = (int*)alloc((size_t)nbuck * BCAP * 4); // ~9.6 MB
    int*   adj     = (int*)alloc((size_t)E * 4);
    int2*  rowinfo = (int2*)alloc((size_t)n * 8);
    float* dinv    = (float*)alloc((size_t)n * 4);
    unsigned short* hs1 = (unsigned short*)alloc((size_t)n * FP * 2);
    unsigned short* hs2 = (unsigned short*)alloc((size_t)n * FP * 2);
    unsigned short* h1b = (unsigned short*)alloc((size_t)n * FP * 2);

    hipMemsetAsync(gcur, 0, (size_t)(NBMAX + 1) * 4, stream);
    k_partmm1<<<nchunks + nmm, 256, 0, stream>>>(src, dst, gcur, pairs, E, nchunks,
                                                 x, W1, hs1, n);
    k_build<<<nbuck, 256, 0, stream>>>(gcur, pairs, gcur + NBMAX, adj, rowinfo,
                                       dinv, hs1, n);
    k_agg1<<<nagg, 256, 0, stream>>>(rowinfo, adj, hs1, dinv, b1, h1b, n, E);
    k_mm2<<<nmm, 256, 0, stream>>>(h1b, W2, dinv, hs2, n);
    k_agg2<<<nagg, 256, 0, stream>>>(rowinfo, adj, hs2, dinv, b2, out, n, E);
}